// Round 1
// baseline (25744.391 us; speedup 1.0000x reference)
//
#include <hip/hip_runtime.h>
#include <cmath>

#define L_     10
#define R_     64
#define G_     128
#define S_     256
#define MEL_   80
#define NCLS_  256
#define HOP_   64
#define END_   256
#define FRAMES_ 8
#define T_     512

__device__ __forceinline__ float dot4(float4 a, float4 b, float acc) {
  acc = fmaf(a.x, b.x, acc);
  acc = fmaf(a.y, b.y, acc);
  acc = fmaf(a.z, b.z, acc);
  acc = fmaf(a.w, b.w, acc);
  return acc;
}

// cond8[f][row] = dot(condition_W[row,:], y[:,f]) ; only 8 distinct time-columns
__global__ void cond_prep_kernel(const float* __restrict__ condW,
                                 const float* __restrict__ y,
                                 float* __restrict__ cond8) {
  int idx = blockIdx.x * blockDim.x + threadIdx.x;
  if (idx >= FRAMES_ * L_ * G_) return;
  int f = idx / (L_ * G_);
  int row = idx - f * (L_ * G_);
  float acc = 0.f;
  for (int m = 0; m < MEL_; ++m)
    acc = fmaf(condW[row * MEL_ + m], y[m * FRAMES_ + f], acc);
  cond8[f * (L_ * G_) + row] = acc;
}

__global__ __launch_bounds__(1024) void wavenet_seq_kernel(
    const float* __restrict__ samples,
    const int*   __restrict__ c_ptr,
    const float* __restrict__ emb,
    const float* __restrict__ WVp,
    const float* __restrict__ WVx,
    const float* __restrict__ Wo,
    const float* __restrict__ Wob,
    const float* __restrict__ Wol,
    const float* __restrict__ Wobl,
    const float* __restrict__ e1w,
    const float* __restrict__ e1b,
    const float* __restrict__ e2w,
    const float* __restrict__ e2b,
    const float* __restrict__ cond8,
    float* __restrict__ hist,   // [L][T][R], zero-initialized
    int* __restrict__ out) {

  __shared__ __align__(16) float xb[2][R_];
  __shared__ __align__(16) float past_s[R_];
  __shared__ __align__(16) float z_s[R_];
  __shared__ __align__(16) float skip_s[S_];
  __shared__ __align__(16) float hid_s[END_];
  __shared__ __align__(16) float logits_s[NCLS_];
  __shared__ float wred[4], wsum[4];
  __shared__ int wcand[4];
  __shared__ int prev_s;

  const int tid = threadIdx.x;
  const int lane = tid & 63;
  const int wv = tid >> 6;
  const float cf = (float)c_ptr[0];

  if (tid == 0) prev_s = NCLS_ / 2 - 1;
  __syncthreads();

  for (int t = 0; t < T_; ++t) {
    const int f = t >> 6;  // t / HOP
    const float* condt = cond8 + f * (L_ * G_);

    // ---- S0: x = emb[prev]; prefetch past for layer 0 (dil=1); zero skip ----
    if (tid < 64) {
      xb[0][tid] = emb[prev_s * R_ + tid];
    } else if (tid < 128) {
      int tp = t - 1;
      past_s[tid - 64] = (tp >= 0) ? hist[(0 * T_ + tp) * R_ + (tid - 64)] : 0.f;
    } else if (tid < 128 + S_) {
      skip_s[tid - 128] = 0.f;
    }
    __syncthreads();

    for (int j = 0; j < L_; ++j) {
      const int p = j & 1;
      // ---- phase B: h = cond + WVp@past + WVx@x ; z = tanh(zw)*sigmoid(zf) ----
      {
        const int r  = tid >> 4;         // 0..63 (output gate channel pair index)
        const int s  = tid & 15;         // 16 threads per r: 8 for zw row, 8 for zf row
        const int s0 = s & 7;
        const int row = r + ((s >> 3) << 6);   // r (s<8) or r+64 (s>=8)
        const float* wbase = WVp + ((size_t)(j * G_ + row) * R_) + s0 * 8;
        const float* xbase = WVx + ((size_t)(j * G_ + row) * R_) + s0 * 8;
        const float4* wp4 = (const float4*)wbase;
        const float4* wx4 = (const float4*)xbase;
        const float4* pa4 = (const float4*)(past_s + s0 * 8);
        const float4* xa4 = (const float4*)(xb[p] + s0 * 8);
        float v = 0.f;
        v = dot4(wp4[0], pa4[0], v);
        v = dot4(wp4[1], pa4[1], v);
        v = dot4(wx4[0], xa4[0], v);
        v = dot4(wx4[1], xa4[1], v);
        v += __shfl_down(v, 4, 8);
        v += __shfl_down(v, 2, 8);
        v += __shfl_down(v, 1, 8);
        float vc = v + condt[j * G_ + row];
        float other = __shfl_down(vc, 8, 16);  // zf-side sum to the zw-side lane
        if (s == 0) {
          z_s[r] = tanhf(vc) * (1.f / (1.f + expf(-other)));
        }
        if (s == 1) {
          // written[j] = x (the INPUT to layer j) -> hist[j][t][r]
          hist[((size_t)j * T_ + t) * R_ + r] = xb[p][r];
        }
      }
      __syncthreads();

      // ---- phase C: o = W_o[j] @ z + b ; x += o[:R]; skip += o[R:] ----
      if (j < L_ - 1) {
        if (tid < 640) {
          const int o = tid >> 1, s1 = tid & 1;
          const float4* wr4 = (const float4*)(Wo + ((size_t)(j * (R_ + S_) + o) * R_) + s1 * 32);
          const float4* z4 = (const float4*)(z_s + s1 * 32);
          float v = 0.f;
          #pragma unroll
          for (int k = 0; k < 8; ++k) v = dot4(wr4[k], z4[k], v);
          v += __shfl_down(v, 1, 2);
          if (s1 == 0) {
            float val = v + Wob[j * (R_ + S_) + o];
            if (o < R_) xb[1 - p][o] = xb[p][o] + val;
            else        skip_s[o - R_] += val;
          }
        } else if (tid < 704) {
          // prefetch past for layer j+1 on otherwise-idle lanes
          const int r = tid - 640;
          const int dil = 1 << (j + 1);
          int tp = t - dil;
          past_s[r] = (tp >= 0) ? hist[((size_t)(j + 1) * T_ + tp) * R_ + r] : 0.f;
        }
      } else {
        if (tid < 512) {
          const int o = tid >> 1, s1 = tid & 1;
          const float4* wr4 = (const float4*)(Wol + (size_t)o * R_ + s1 * 32);
          const float4* z4 = (const float4*)(z_s + s1 * 32);
          float v = 0.f;
          #pragma unroll
          for (int k = 0; k < 8; ++k) v = dot4(wr4[k], z4[k], v);
          v += __shfl_down(v, 1, 2);
          if (s1 == 0) skip_s[o] += v + Wobl[o];
        }
      }
      __syncthreads();
    }

    // ---- E1: hid = relu(e1w @ relu(skip) + e1b) ----
    {
      const int o = tid >> 2, s = tid & 3;
      const float4* wr4 = (const float4*)(e1w + (size_t)o * S_ + s * 64);
      const float4* sk4 = (const float4*)(skip_s + s * 64);
      float v = 0.f;
      #pragma unroll
      for (int k = 0; k < 16; ++k) {
        float4 b = sk4[k];
        b.x = fmaxf(b.x, 0.f); b.y = fmaxf(b.y, 0.f);
        b.z = fmaxf(b.z, 0.f); b.w = fmaxf(b.w, 0.f);
        v = dot4(wr4[k], b, v);
      }
      v += __shfl_down(v, 2, 4);
      v += __shfl_down(v, 1, 4);
      if (s == 0) hid_s[o] = fmaxf(v + e1b[o], 0.f);
    }
    __syncthreads();

    // ---- E2: logits = (e2w @ hid + e2b) * c ----
    {
      const int o = tid >> 2, s = tid & 3;
      const float4* wr4 = (const float4*)(e2w + (size_t)o * END_ + s * 64);
      const float4* h4 = (const float4*)(hid_s + s * 64);
      float v = 0.f;
      #pragma unroll
      for (int k = 0; k < 16; ++k) v = dot4(wr4[k], h4[k], v);
      v += __shfl_down(v, 2, 4);
      v += __shfl_down(v, 1, 4);
      if (s == 0) logits_s[o] = (v + e2b[o]) * cf;
    }
    __syncthreads();

    // ---- sampling: new = first index where cumsum(softmax) > s, else 0 ----
    float lg = 0.f, csum = 0.f;
    if (tid < NCLS_) {
      lg = logits_s[tid];
      float m = lg;
      #pragma unroll
      for (int off = 32; off >= 1; off >>= 1) m = fmaxf(m, __shfl_xor(m, off, 64));
      if (lane == 0) wred[wv] = m;
    }
    __syncthreads();
    if (tid < NCLS_) {
      float m = fmaxf(fmaxf(wred[0], wred[1]), fmaxf(wred[2], wred[3]));
      float e = expf(lg - m);
      csum = e;
      #pragma unroll
      for (int off = 1; off < 64; off <<= 1) {
        float o_ = __shfl_up(csum, off, 64);
        if (lane >= off) csum += o_;
      }
      if (lane == 63) wsum[wv] = csum;
    }
    __syncthreads();
    if (tid < NCLS_) {
      float total = wsum[0] + wsum[1] + wsum[2] + wsum[3];
      float offset = 0.f;
      for (int w2 = 0; w2 < wv; ++w2) offset += wsum[w2];
      float cum = offset + csum;
      float thresh = samples[t] * total;
      bool flag = cum > thresh;
      unsigned long long mask = __ballot(flag);
      if (lane == 0) wcand[wv] = mask ? (wv * 64 + __ffsll(mask) - 1) : 100000;
    }
    __syncthreads();
    if (tid == 0) {
      int nw = min(min(wcand[0], wcand[1]), min(wcand[2], wcand[3]));
      if (nw >= 100000) nw = 0;   // jnp.argmax of all-False -> 0
      out[t] = nw;
      prev_s = nw;
    }
    __syncthreads();
  }
}

extern "C" void kernel_launch(void* const* d_in, const int* in_sizes, int n_in,
                              void* d_out, int out_size, void* d_ws, size_t ws_size,
                              hipStream_t stream) {
  const float* y       = (const float*)d_in[0];
  const float* samples = (const float*)d_in[1];
  const int*   c       = (const int*)d_in[2];
  const float* emb     = (const float*)d_in[3];
  const float* condW   = (const float*)d_in[4];
  const float* WVp     = (const float*)d_in[5];
  const float* WVx     = (const float*)d_in[6];
  const float* Wo      = (const float*)d_in[7];
  const float* Wob     = (const float*)d_in[8];
  const float* Wol     = (const float*)d_in[9];
  const float* Wobl    = (const float*)d_in[10];
  const float* e1w     = (const float*)d_in[11];
  const float* e1b     = (const float*)d_in[12];
  const float* e2w     = (const float*)d_in[13];
  const float* e2b     = (const float*)d_in[14];

  float* cond8 = (float*)d_ws;                       // 8*1280 floats
  float* hist  = cond8 + FRAMES_ * L_ * G_;          // L*T*R floats
  int*   out   = (int*)d_out;

  // hist must be zero (ws is re-poisoned before every launch)
  hipMemsetAsync(hist, 0, (size_t)L_ * T_ * R_ * sizeof(float), stream);

  cond_prep_kernel<<<(FRAMES_ * L_ * G_ + 255) / 256, 256, 0, stream>>>(condW, y, cond8);

  wavenet_seq_kernel<<<1, 1024, 0, stream>>>(samples, c, emb, WVp, WVx, Wo, Wob,
                                             Wol, Wobl, e1w, e1b, e2w, e2b,
                                             cond8, hist, out);
}

// Round 2
// 15240.202 us; speedup vs baseline: 1.6892x; 1.6892x over previous
//
#include <hip/hip_runtime.h>
#include <cmath>

#define L_     10
#define R_     64
#define G_     128
#define S_     256
#define MEL_   80
#define NCLS_  256
#define HOP_   64
#define END_   256
#define FRAMES_ 8
#define T_     512

// ---- workspace layout (float offsets) ----
#define COND8_OFF   0                               // 8*1280
#define HIST_OFF    10240                           // layers 1..8: [(j-1)][512][64]
#define MBX_OFF     (HIST_OFF + 8*T_*R_)            // [10][320]: mbx[j] = input to B_j (x 64 | skip 256)
#define MBSKIP_OFF  (MBX_OFF + 10*320)              // [256]
#define MBHID_OFF   (MBSKIP_OFF + 256)              // [256]
#define MBLOG_OFF   (MBHID_OFF + 256)               // [128]
#define FLAG_OFF    (MBLOG_OFF + 128)               // 16 flags, 16 ints apart (64B)

#define FID_SKIP   10
#define FID_HID0   11
#define FID_HID1   12
#define FID_LOG    13
#define FID_PREV   14

__device__ __forceinline__ int flag_ld(const int* p) {
  return __hip_atomic_load(p, __ATOMIC_RELAXED, __HIP_MEMORY_SCOPE_AGENT);
}
__device__ __forceinline__ void wait_flag(const int* p, int want) {
  while (flag_ld(p) < want) {}
  (void)__hip_atomic_load(p, __ATOMIC_ACQUIRE, __HIP_MEMORY_SCOPE_AGENT);
}
__device__ __forceinline__ int wait_prev(const int* p, int want) {
  int v;
  while ((int)((unsigned)(v = flag_ld(p)) >> 16) < want) {}
  (void)__hip_atomic_load(p, __ATOMIC_ACQUIRE, __HIP_MEMORY_SCOPE_AGENT);
  return v & 0xffff;
}
__device__ __forceinline__ void set_flag(int* p, int v) {
  __hip_atomic_store(p, v, __ATOMIC_RELEASE, __HIP_MEMORY_SCOPE_AGENT);
}

#define DOTREG(N4, W, V4, ACC) do { \
  _Pragma("unroll") \
  for (int k_ = 0; k_ < (N4); ++k_) { float4 a_ = (V4)[k_]; \
    ACC = fmaf((W)[4*k_+0], a_.x, ACC); ACC = fmaf((W)[4*k_+1], a_.y, ACC); \
    ACC = fmaf((W)[4*k_+2], a_.z, ACC); ACC = fmaf((W)[4*k_+3], a_.w, ACC); } \
} while (0)

#define DOTREG_RELU(N4, W, V4, ACC) do { \
  _Pragma("unroll") \
  for (int k_ = 0; k_ < (N4); ++k_) { float4 a_ = (V4)[k_]; \
    a_.x = fmaxf(a_.x, 0.f); a_.y = fmaxf(a_.y, 0.f); \
    a_.z = fmaxf(a_.z, 0.f); a_.w = fmaxf(a_.w, 0.f); \
    ACC = fmaf((W)[4*k_+0], a_.x, ACC); ACC = fmaf((W)[4*k_+1], a_.y, ACC); \
    ACC = fmaf((W)[4*k_+2], a_.z, ACC); ACC = fmaf((W)[4*k_+3], a_.w, ACC); } \
} while (0)

__global__ void cond_prep_kernel(const float* __restrict__ condW,
                                 const float* __restrict__ y,
                                 float* __restrict__ cond8) {
  int idx = blockIdx.x * blockDim.x + threadIdx.x;
  if (idx >= FRAMES_ * L_ * G_) return;
  int f = idx / (L_ * G_);
  int row = idx - f * (L_ * G_);
  float acc = 0.f;
  for (int m = 0; m < MEL_; ++m)
    acc = fmaf(condW[row * MEL_ + m], y[m * FRAMES_ + f], acc);
  cond8[f * (L_ * G_) + row] = acc;
}

__global__ __launch_bounds__(256, 1) void wavenet_pipe(
    const float* __restrict__ samples,
    const int*   __restrict__ c_ptr,
    const float* __restrict__ emb,
    const float* __restrict__ WVp,
    const float* __restrict__ WVx,
    const float* __restrict__ Wo,
    const float* __restrict__ Wob,
    const float* __restrict__ Wol,
    const float* __restrict__ Wobl,
    const float* __restrict__ e1w,
    const float* __restrict__ e1b,
    const float* __restrict__ e2w,
    const float* __restrict__ e2b,
    float* __restrict__ ws,
    int*   __restrict__ out) {

  const int bid = blockIdx.x;
  const int tid = threadIdx.x;

  float* cond8  = ws + COND8_OFF;
  float* hist   = ws + HIST_OFF;
  float* mbx    = ws + MBX_OFF;
  float* mbskip = ws + MBSKIP_OFF;
  float* mbhid  = ws + MBHID_OFF;
  float* mblog  = ws + MBLOG_OFF;
  int*   flags  = (int*)(ws + FLAG_OFF);

  __shared__ __align__(16) float x_s[R_];
  __shared__ __align__(16) float past_s[R_];
  __shared__ __align__(16) float h_s[G_];
  __shared__ __align__(16) float z_s[R_];
  __shared__ __align__(16) float pd_s[G_];
  __shared__ __align__(16) float cond_s[FRAMES_ * G_];   // D1 reuses as logits
  __shared__ __align__(16) float vec_s[S_];              // skip / hid staging
  __shared__ float wred[4], wsum[4];
  __shared__ int wcand[4];

  if (bid < 10) {
    // ======================= layer stage B_j =======================
    const int j = bid;
    const int row = tid >> 1, half = tid & 1;
    const int dil = 1 << j;

    float wp[32], wx[32], wo0[64], wo1[64];
    float b0 = 0.f, b1 = 0.f;
    {
      const float* p = WVx + ((size_t)(j * G_ + row)) * R_ + half * 32;
      #pragma unroll
      for (int k = 0; k < 32; ++k) wx[k] = p[k];
    }
    if (j < 9) {
      const float* p = WVp + ((size_t)(j * G_ + row)) * R_ + half * 32;
      #pragma unroll
      for (int k = 0; k < 32; ++k) wp[k] = p[k];
      const float* q = Wo + ((size_t)(j * (R_ + S_) + tid)) * R_;
      #pragma unroll
      for (int k = 0; k < 64; ++k) wo0[k] = q[k];
      b0 = Wob[j * (R_ + S_) + tid];
      if (tid < 64) {
        const float* q2 = Wo + ((size_t)(j * (R_ + S_) + 256 + tid)) * R_;
        #pragma unroll
        for (int k = 0; k < 64; ++k) wo1[k] = q2[k];
        b1 = Wob[j * (R_ + S_) + 256 + tid];
      }
    } else {
      const float* q = Wol + (size_t)tid * R_;
      #pragma unroll
      for (int k = 0; k < 64; ++k) wo0[k] = q[k];
      b0 = Wobl[tid];
    }
    for (int i = tid; i < FRAMES_ * G_; i += 256)
      cond_s[i] = cond8[(i >> 7) * (L_ * G_) + j * G_ + (i & 127)];
    __syncthreads();
    if (tid < G_) pd_s[tid] = cond_s[tid];  // t=0: past term is 0, f=0

    const float* inx   = mbx + (size_t)j * 320;
    const float* insk  = mbx + (size_t)j * 320 + 64;
    float* outx  = (j < 9) ? (mbx + (size_t)(j + 1) * 320) : nullptr;
    float* outsk = (j < 9) ? (mbx + (size_t)(j + 1) * 320 + 64) : mbskip;
    int* inflag   = flags + j * 16;                  // valid for j>=1
    int* prevflag = flags + FID_PREV * 16;
    int* outflag  = (j < 9) ? (flags + (j + 1) * 16) : (flags + FID_SKIP * 16);
    float* myhist = (j >= 1 && j < 9) ? (hist + (size_t)(j - 1) * T_ * R_) : nullptr;

    for (int t = 0; t < T_; ++t) {
      // -- acquire input, stage x into LDS (wave 0 spins; others park at barrier)
      if (tid < 64) {
        if (j == 0) {
          int prev = 127;
          if (t > 0) prev = wait_prev(prevflag, t);
          if (tid < 16)
            ((float4*)x_s)[tid] = ((const float4*)(emb + (size_t)prev * R_))[tid];
        } else {
          wait_flag(inflag, t + 1);
          if (tid < 16) ((float4*)x_s)[tid] = ((const float4*)inx)[tid];
        }
      }
      __syncthreads();

      // -- gates: h = pd_s (past-dot + cond, precomputed) + WVx @ x
      {
        float v = 0.f;
        const float4* xs4 = (const float4*)(x_s + half * 32);
        DOTREG(8, wx, xs4, v);
        v += __shfl_down(v, 1, 2);
        if (half == 0) h_s[row] = v + pd_s[row];
      }
      if (myhist && tid < 16)  // dilation ring write (fire & forget)
        ((float4*)(myhist + (size_t)t * R_))[tid] = ((const float4*)x_s)[tid];
      __syncthreads();

      if (tid < 64) {
        float hw = h_s[tid], hf = h_s[tid + 64];
        z_s[tid] = tanhf(hw) * (1.f / (1.f + expf(-hf)));
      }
      __syncthreads();

      // -- W_o @ z, residual + skip accumulate, publish
      {
        float skin0 = 0.f, skin1 = 0.f;
        if (j > 0 && j < 9) {
          if (tid >= 64) skin0 = insk[tid - 64];
          else           skin1 = insk[192 + tid];
        }
        float v0 = 0.f;
        const float4* z4 = (const float4*)z_s;
        DOTREG(16, wo0, z4, v0);
        if (j < 9) {
          if (tid < 64) {
            float v1 = 0.f;
            DOTREG(16, wo1, z4, v1);
            outx[tid] = x_s[tid] + v0 + b0;
            outsk[192 + tid] = skin1 + v1 + b1;
          } else {
            outsk[tid - 64] = skin0 + v0 + b0;
          }
        } else {
          float skin = insk[tid];
          outsk[tid] = skin + v0 + b0;
        }
      }
      __syncthreads();
      if (tid == 0) set_flag(outflag, t + 1);

      // -- off-critical-path: precompute past-dot + cond for t+1
      const int tn = t + 1;
      if (tn < T_) {
        const int f1 = tn >> 6;
        if (j == 0) {
          float v = 0.f;
          const float4* ps4 = (const float4*)(x_s + half * 32);  // past(t+1) = x(t)
          DOTREG(8, wp, ps4, v);
          v += __shfl_down(v, 1, 2);
          if (half == 0) pd_s[row] = v + cond_s[f1 * G_ + row];
        } else if (j < 9) {
          const int tp = tn - dil;
          if (tid < 16) {
            float4 pv = make_float4(0.f, 0.f, 0.f, 0.f);
            if (tp >= 0) pv = ((const float4*)(myhist + (size_t)tp * R_))[tid];
            ((float4*)past_s)[tid] = pv;
          }
          __syncthreads();
          float v = 0.f;
          const float4* ps4 = (const float4*)(past_s + half * 32);
          DOTREG(8, wp, ps4, v);
          v += __shfl_down(v, 1, 2);
          if (half == 0) pd_s[row] = v + cond_s[f1 * G_ + row];
        } else {
          if (tid < G_) pd_s[tid] = cond_s[f1 * G_ + tid];
        }
      }
      // next iteration's post-spin barrier orders pd_s for the gate readers
    }

  } else if (bid < 12) {
    // ======================= E1 stage C_h =======================
    const int h = bid - 10;
    const int o_loc = tid >> 1, halfc = tid & 1;
    float w[128];
    {
      const float* p = e1w + ((size_t)(h * 128 + o_loc)) * S_ + halfc * 128;
      #pragma unroll
      for (int k = 0; k < 128; ++k) w[k] = p[k];
    }
    const float bias = e1b[h * 128 + o_loc];
    int* inflag  = flags + FID_SKIP * 16;
    int* outflag = flags + ((h == 0) ? FID_HID0 : FID_HID1) * 16;
    float* outp = mbhid + h * 128;

    for (int t = 0; t < T_; ++t) {
      if (tid < 64) {
        wait_flag(inflag, t + 1);
        ((float4*)vec_s)[tid] = ((const float4*)mbskip)[tid];
      }
      __syncthreads();
      float v = 0.f;
      const float4* s4 = (const float4*)(vec_s + halfc * 128);
      DOTREG_RELU(32, w, s4, v);
      v += __shfl_down(v, 1, 2);
      if (halfc == 0) outp[o_loc] = fmaxf(v + bias, 0.f);
      __syncthreads();
      if (tid == 0) set_flag(outflag, t + 1);
    }

  } else {
    // ======================= E2 stage D_h (D1 samples) =======================
    const int h = bid - 12;
    const int o_loc = tid >> 1, halfc = tid & 1;
    const float cf = (float)c_ptr[0];
    float w[128];
    {
      const float* p = e2w + ((size_t)(h * 128 + o_loc)) * END_ + halfc * 128;
      #pragma unroll
      for (int k = 0; k < 128; ++k) w[k] = p[k];
    }
    const float bias = e2b[h * 128 + o_loc];
    int* f0    = flags + FID_HID0 * 16;
    int* f1p   = flags + FID_HID1 * 16;
    int* flog  = flags + FID_LOG * 16;
    int* fprev = flags + FID_PREV * 16;
    float* logits_s = cond_s;  // reuse (unused by D stages)
    const int lane = tid & 63, wv = tid >> 6;

    for (int t = 0; t < T_; ++t) {
      if (tid < 64) {
        wait_flag(f0, t + 1);
        wait_flag(f1p, t + 1);
        ((float4*)vec_s)[tid] = ((const float4*)mbhid)[tid];
      }
      __syncthreads();
      float v = 0.f;
      const float4* h4 = (const float4*)(vec_s + halfc * 128);
      DOTREG(32, w, h4, v);
      v += __shfl_down(v, 1, 2);

      if (h == 0) {
        if (halfc == 0) mblog[o_loc] = (v + bias) * cf;
        __syncthreads();
        if (tid == 0) set_flag(flog, t + 1);
      } else {
        if (halfc == 0) logits_s[128 + o_loc] = (v + bias) * cf;
        if (tid < 64) {
          wait_flag(flog, t + 1);
          if (tid < 32) ((float4*)logits_s)[tid] = ((const float4*)mblog)[tid];
        }
        __syncthreads();

        // ---- softmax-CDF sampling over 256 logits ----
        float lg = logits_s[tid];
        float m = lg;
        #pragma unroll
        for (int off = 32; off >= 1; off >>= 1) m = fmaxf(m, __shfl_xor(m, off, 64));
        if (lane == 0) wred[wv] = m;
        __syncthreads();
        m = fmaxf(fmaxf(wred[0], wred[1]), fmaxf(wred[2], wred[3]));
        float e = expf(lg - m);
        float cs = e;
        #pragma unroll
        for (int off = 1; off < 64; off <<= 1) {
          float o_ = __shfl_up(cs, off, 64);
          if (lane >= off) cs += o_;
        }
        if (lane == 63) wsum[wv] = cs;
        __syncthreads();
        float total = wsum[0] + wsum[1] + wsum[2] + wsum[3];
        float offv = 0.f;
        for (int w2 = 0; w2 < wv; ++w2) offv += wsum[w2];
        float thresh = samples[t] * total;
        bool flagb = (offv + cs) > thresh;
        unsigned long long mk = __ballot(flagb);
        if (lane == 0) wcand[wv] = mk ? (wv * 64 + __ffsll(mk) - 1) : 100000;
        __syncthreads();
        if (tid == 0) {
          int nw = min(min(wcand[0], wcand[1]), min(wcand[2], wcand[3]));
          if (nw >= 100000) nw = 0;  // argmax of all-False -> 0
          out[t] = nw;
          set_flag(fprev, ((t + 1) << 16) | nw);
        }
        __syncthreads();  // protect wred/wsum/logits_s before next step
      }
    }
  }
}

extern "C" void kernel_launch(void* const* d_in, const int* in_sizes, int n_in,
                              void* d_out, int out_size, void* d_ws, size_t ws_size,
                              hipStream_t stream) {
  const float* y       = (const float*)d_in[0];
  const float* samples = (const float*)d_in[1];
  const int*   c       = (const int*)d_in[2];
  const float* emb     = (const float*)d_in[3];
  const float* condW   = (const float*)d_in[4];
  const float* WVp     = (const float*)d_in[5];
  const float* WVx     = (const float*)d_in[6];
  const float* Wo      = (const float*)d_in[7];
  const float* Wob     = (const float*)d_in[8];
  const float* Wol     = (const float*)d_in[9];
  const float* Wobl    = (const float*)d_in[10];
  const float* e1w     = (const float*)d_in[11];
  const float* e1b     = (const float*)d_in[12];
  const float* e2w     = (const float*)d_in[13];
  const float* e2b     = (const float*)d_in[14];

  float* ws  = (float*)d_ws;
  int*   out = (int*)d_out;

  // flags must start at 0 every launch (ws is re-poisoned to 0xAA)
  hipMemsetAsync((char*)d_ws + (size_t)FLAG_OFF * sizeof(float), 0,
                 16 * 16 * sizeof(int), stream);

  cond_prep_kernel<<<(FRAMES_ * L_ * G_ + 255) / 256, 256, 0, stream>>>(
      condW, y, ws + COND8_OFF);

  wavenet_pipe<<<14, 256, 0, stream>>>(samples, c, emb, WVp, WVx, Wo, Wob,
                                       Wol, Wobl, e1w, e1b, e2w, e2b, ws, out);
}